// Round 10
// baseline (1560.173 us; speedup 1.0000x reference)
//
#include <hip/hip_runtime.h>
#include <hip/hip_bf16.h>

typedef __attribute__((ext_vector_type(8))) short short8;
typedef __attribute__((ext_vector_type(4))) float f32x4;
typedef unsigned short u16;
typedef unsigned long long u64;

__device__ __forceinline__ u16 f2b(float f) {
    unsigned u = __float_as_uint(f);
    return (u16)((u + 0x7FFFu + ((u >> 16) & 1u)) >> 16);
}
__device__ __forceinline__ float b2f(u16 u) {
    return __uint_as_float(((unsigned)u) << 16);
}
__device__ __forceinline__ void gload16(const void* g, void* l) {
    __builtin_amdgcn_global_load_lds(
        (const __attribute__((address_space(1))) void*)g,
        (__attribute__((address_space(3))) void*)l, 16, 0, 0);
}

// ---------------------------------------------------------------------------
// f32 -> bf16 bulk convert
// ---------------------------------------------------------------------------
__global__ __launch_bounds__(256)
void k_f2b(const float* __restrict__ s, u16* __restrict__ d, int n4)
{
    int i = blockIdx.x * 256 + threadIdx.x;
    if (i >= n4) return;
    float4 v = ((const float4*)s)[i];
    short4 o;
    o.x = (short)f2b(v.x); o.y = (short)f2b(v.y);
    o.z = (short)f2b(v.z); o.w = (short)f2b(v.w);
    ((short4*)d)[i] = o;
}

// ---------------------------------------------------------------------------
// Embedding gather -> bf16
// ---------------------------------------------------------------------------
__global__ __launch_bounds__(256)
void k_embed(const int* __restrict__ tok, const float* __restrict__ emb,
             u16* __restrict__ x0)
{
    int i = blockIdx.x * 256 + threadIdx.x;   // 131072: 4 elems each
    int n = i >> 7, p4 = i & 127;
    float4 v = ((const float4*)(emb + (size_t)tok[n] * 512))[p4];
    short4 o;
    o.x = (short)f2b(v.x); o.y = (short)f2b(v.y);
    o.z = (short)f2b(v.z); o.w = (short)f2b(v.w);
    ((short4*)x0)[i] = o;
}

// ---------------------------------------------------------------------------
// MFMA bf16 GEMM (m97-style): C[M,N] = A[M,K](bf16) * B[N,K]^T + bias
// Block 128x128, 4 waves (2x2), wave tile 64x64, K-step 32, linear LDS,
// A staged via global_load_lds (width 16).
// BIN=1: B bf16 (global_load_lds). BIN=0: B f32, reg-convert stage.
// EPI=0: C f32. EPI=1: latent head -> bf16, remap (e,p), tanh*gain.
// EPI=2: decoder: store bf16 exp(min(v,80)); atomicAdd per-row sums to rsum.
// ---------------------------------------------------------------------------
template <int EPI, int BIN>
__global__ __launch_bounds__(256)
void k_gemm(const u16* __restrict__ A, const void* __restrict__ Bp,
            const float* __restrict__ bias, void* __restrict__ Cp,
            int M, int N, int K, const float* __restrict__ gain,
            float* __restrict__ rsum)
{
    __shared__ __align__(16) u16 As[128 * 32];
    __shared__ __align__(16) u16 Bs[128 * 32];
    __shared__ float rs[2][128];
    const int tid = threadIdx.x;
    const int lane = tid & 63, wid = tid >> 6;
    const int wr = wid >> 1, wc = wid & 1;
    const int l15 = lane & 15, l4 = lane >> 4;
    const int row0 = blockIdx.y * 128, col0 = blockIdx.x * 128;

    const int srA = wid * 16 + (lane >> 2);
    const int skA = (lane & 3) * 8;
    const int srow = tid >> 1, skh = (tid & 1) << 4;

    f32x4 acc[4][4] = {};

    for (int k0 = 0; k0 < K; k0 += 32) {
        if (k0) __syncthreads();
        gload16(A + (size_t)(row0 + srA) * K + k0 + skA, As + wid * 512);
        gload16(A + (size_t)(row0 + 64 + srA) * K + k0 + skA, As + 2048 + wid * 512);
        if (BIN == 1) {
            const u16* B = (const u16*)Bp;
            gload16(B + (size_t)(col0 + srA) * K + k0 + skA, Bs + wid * 512);
            gload16(B + (size_t)(col0 + 64 + srA) * K + k0 + skA, Bs + 2048 + wid * 512);
        } else {
            const float* B = (const float*)Bp;
            const float4* sb = (const float4*)(B + (size_t)(col0 + srow) * K + k0 + skh);
            float tmp[16];
            *(float4*)&tmp[0]  = sb[0];
            *(float4*)&tmp[4]  = sb[1];
            *(float4*)&tmp[8]  = sb[2];
            *(float4*)&tmp[12] = sb[3];
            short8 v0, v1;
#pragma unroll
            for (int i = 0; i < 8; ++i) { v0[i] = (short)f2b(tmp[i]); v1[i] = (short)f2b(tmp[8 + i]); }
            *(short8*)&Bs[srow * 32 + skh]     = v0;
            *(short8*)&Bs[srow * 32 + skh + 8] = v1;
        }
        __syncthreads();

        short8 af[4], bfv[4];
#pragma unroll
        for (int i = 0; i < 4; ++i)
            af[i]  = *(const short8*)&As[(wr * 64 + i * 16 + l15) * 32 + l4 * 8];
#pragma unroll
        for (int i = 0; i < 4; ++i)
            bfv[i] = *(const short8*)&Bs[(wc * 64 + i * 16 + l15) * 32 + l4 * 8];
#pragma unroll
        for (int mi = 0; mi < 4; ++mi)
#pragma unroll
            for (int ni = 0; ni < 4; ++ni)
                acc[mi][ni] = __builtin_amdgcn_mfma_f32_16x16x32_bf16(
                    af[mi], bfv[ni], acc[mi][ni], 0, 0, 0);
    }

    if (EPI == 2) {
#pragma unroll
        for (int mi = 0; mi < 4; ++mi) {
#pragma unroll
            for (int j = 0; j < 4; ++j) {
                int rb = row0 + wr * 64 + mi * 16 + l4 * 4 + j;
                float rsub = 0.f;
#pragma unroll
                for (int ni = 0; ni < 4; ++ni) {
                    int cc = col0 + wc * 64 + ni * 16 + l15;
                    float pv = expf(fminf(acc[mi][ni][j] + bias[cc], 80.f));
                    ((u16*)Cp)[(size_t)rb * N + cc] = f2b(pv);
                    rsub += pv;
                }
#pragma unroll
                for (int o = 1; o < 16; o <<= 1) rsub += __shfl_xor(rsub, o, 64);
                if (l15 == 0)
                    rs[wc][wr * 64 + mi * 16 + l4 * 4 + j] = rsub;
            }
        }
        __syncthreads();
        if (tid < 128)
            atomicAdd(&rsum[row0 + tid], rs[0][tid] + rs[1][tid]);
        return;
    }

#pragma unroll
    for (int mi = 0; mi < 4; ++mi) {
#pragma unroll
        for (int ni = 0; ni < 4; ++ni) {
            int rb = row0 + wr * 64 + mi * 16 + l4 * 4;
            int cc = col0 + wc * 64 + ni * 16 + l15;
            float bv = bias[cc];
#pragma unroll
            for (int j = 0; j < 4; ++j) {
                float v = acc[mi][ni][j] + bv;
                if (EPI == 0) {
                    ((float*)Cp)[(size_t)(rb + j) * N + cc] = v;
                } else {
                    int e = cc >> 9, pp = cc & 511;
                    ((u16*)Cp)[(((size_t)(rb + j) * 8 + e) << 9) | pp] =
                        f2b(tanhf(v) * gain[pp]);
                }
            }
        }
    }
}

// ---------------------------------------------------------------------------
// Decoder GEMM, 256x256 tile, 512 threads (8 waves, 2(M)x4(N), wave tile
// 128x64). pe[r][v] = bf16(exp(min(logit,80))), rowsum[row0+r] += partials.
// M%256==0, N%256==0, K%32==0. Same verified staging geometry (linear LDS).
// ---------------------------------------------------------------------------
__global__ __launch_bounds__(512)
void k_gemm_dec2(const u16* __restrict__ A, const u16* __restrict__ B,
                 const float* __restrict__ bias, u16* __restrict__ pe,
                 int M, int N, int K, float* __restrict__ rsum)
{
    __shared__ __align__(16) u16 As[256 * 32];
    __shared__ __align__(16) u16 Bs[256 * 32];
    __shared__ float rs[4][256];
    const int tid = threadIdx.x;
    const int lane = tid & 63, wid = tid >> 6;
    const int wr = wid >> 2, wc = wid & 3;
    const int l15 = lane & 15, l4 = lane >> 4;
    const int row0 = blockIdx.y * 256, col0 = blockIdx.x * 256;

    const int srA = wid * 16 + (lane >> 2);    // rows 0..127 per slot
    const int skA = (lane & 3) * 8;

    f32x4 acc[8][4] = {};

    for (int k0 = 0; k0 < K; k0 += 32) {
        if (k0) __syncthreads();
        gload16(A + (size_t)(row0 + srA) * K + k0 + skA, As + wid * 512);
        gload16(A + (size_t)(row0 + 128 + srA) * K + k0 + skA, As + 4096 + wid * 512);
        gload16(B + (size_t)(col0 + srA) * K + k0 + skA, Bs + wid * 512);
        gload16(B + (size_t)(col0 + 128 + srA) * K + k0 + skA, Bs + 4096 + wid * 512);
        __syncthreads();

        short8 af[8], bfv[4];
#pragma unroll
        for (int i = 0; i < 8; ++i)
            af[i]  = *(const short8*)&As[(wr * 128 + i * 16 + l15) * 32 + l4 * 8];
#pragma unroll
        for (int i = 0; i < 4; ++i)
            bfv[i] = *(const short8*)&Bs[(wc * 64 + i * 16 + l15) * 32 + l4 * 8];
#pragma unroll
        for (int mi = 0; mi < 8; ++mi)
#pragma unroll
            for (int ni = 0; ni < 4; ++ni)
                acc[mi][ni] = __builtin_amdgcn_mfma_f32_16x16x32_bf16(
                    af[mi], bfv[ni], acc[mi][ni], 0, 0, 0);
    }

#pragma unroll
    for (int mi = 0; mi < 8; ++mi) {
#pragma unroll
        for (int j = 0; j < 4; ++j) {
            int rloc = wr * 128 + mi * 16 + l4 * 4 + j;
            float rsub = 0.f;
#pragma unroll
            for (int ni = 0; ni < 4; ++ni) {
                int cc = col0 + wc * 64 + ni * 16 + l15;
                float pv = expf(fminf(acc[mi][ni][j] + bias[cc], 80.f));
                pe[(size_t)(row0 + rloc) * N + cc] = f2b(pv);
                rsub += pv;
            }
#pragma unroll
            for (int o = 1; o < 16; o <<= 1) rsub += __shfl_xor(rsub, o, 64);
            if (l15 == 0) rs[wc][rloc] = rsub;
        }
    }
    __syncthreads();
    if (tid < 256)
        atomicAdd(&rsum[row0 + tid],
                  rs[0][tid] + rs[1][tid] + rs[2][tid] + rs[3][tid]);
}

// ---------------------------------------------------------------------------
// Persistent-weight cooperative LSTM layer, FENCELESS protocol (round-7
// proven, byte-identical). h exchanged through the LLC with relaxed
// agent-scope atomic u64 stores/loads; per-block flag slots; no fences,
// no RMW. W register-resident. Grid = DH/16 blocks x 512 threads.
// ---------------------------------------------------------------------------
template <int DH>
__global__ void __launch_bounds__(512)
k_rnn(const float* __restrict__ xg,    // (1024, 4*DH) f32
      const u16* __restrict__ W,       // (4*DH, DH) bf16
      const float* __restrict__ h0f,   // (16, DH) f32
      const float* __restrict__ c0f,   // (16, DH) f32
      u16* __restrict__ y,             // (1024, DH) bf16
      unsigned* __restrict__ bar,      // nb slots, stride 32 uints, zeroed
      int nb)
{
    constexpr int DH2 = DH / 2;
    constexpr int NSH = DH2 / 32;      // MFMA k-steps per K-half
    constexpr int NL  = 16 * DH / 4 / 512;   // u64 h-loads per thread
    constexpr int RW  = DH / 4;        // u64 per h row
    constexpr int LDH = DH + 8;        // pad -> 2-way banks (free)
    __shared__ __align__(16) u16 hs[16][LDH];
    __shared__ __align__(16) f32x4 red[8][64];
    __shared__ __align__(16) u16 hout[16][16];

    const int tid = threadIdx.x;
    const int lane = tid & 63, wid = tid >> 6;
    const int g = wid & 3, kh = wid >> 2;
    const int l15 = lane & 15, l4 = lane >> 4;
    const int u0 = blockIdx.x * 16;

    // ---- load W fragments into registers (once) ----
    short8 wfr[NSH];
    {
        const u16* wa = W + (size_t)(g * DH + u0 + l15) * DH + kh * DH2 + l4 * 8;
#pragma unroll
        for (int s = 0; s < NSH; ++s) wfr[s] = *(const short8*)(wa + s * 32);
    }

    const int eb = tid >> 4, eu = tid & 15;      // epilogue mapping (tid<256)
    float c_reg = (tid < 256) ? c0f[(size_t)eb * DH + u0 + eu] : 0.f;

    for (int t = 0; t < 64; ++t) {
        // ---- prefetch xg row into regs ----
        float xpre[4];
        if (tid < 256) {
            const float* xr = xg + (size_t)(t * 16 + eb) * 4 * DH + u0 + eu;
#pragma unroll
            for (int gg = 0; gg < 4; ++gg) xpre[gg] = xr[(size_t)gg * DH];
        }

        // ---- wait for producers + stage h_{t-1} into LDS ----
        if (t == 0) {
            for (int i = tid; i < 16 * DH / 4; i += 512) {
                int r = i / (DH / 4), k4 = i % (DH / 4);
                float4 v = *(const float4*)(h0f + (size_t)r * DH + k4 * 4);
                short4 o;
                o.x = (short)f2b(v.x); o.y = (short)f2b(v.y);
                o.z = (short)f2b(v.z); o.w = (short)f2b(v.w);
                *(short4*)&hs[r][k4 * 4] = o;
            }
            __syncthreads();
        } else {
            if (tid < nb) {
                while (__hip_atomic_load(bar + tid * 32, __ATOMIC_RELAXED,
                                         __HIP_MEMORY_SCOPE_AGENT) < (unsigned)t)
                    __builtin_amdgcn_s_sleep(1);
            }
            __syncthreads();
            // coherent h read from LLC (batched -> pipelined loads)
            const u64* hp = (const u64*)(y + (size_t)(t - 1) * 16 * DH);
            u64 tmp[NL];
#pragma unroll
            for (int j = 0; j < NL; ++j)
                tmp[j] = __hip_atomic_load(hp + tid + j * 512, __ATOMIC_RELAXED,
                                           __HIP_MEMORY_SCOPE_AGENT);
#pragma unroll
            for (int j = 0; j < NL; ++j) {
                int idx = tid + j * 512;
                int r = idx / RW, c = (idx % RW) * 4;
                *(u64*)&hs[r][c] = tmp[j];
            }
            __syncthreads();
        }

        // ---- MFMA from register-resident W ----
        f32x4 acc = {};
#pragma unroll
        for (int s = 0; s < NSH; ++s) {
            short8 hf = *(const short8*)&hs[l15][kh * DH2 + s * 32 + l4 * 8];
            acc = __builtin_amdgcn_mfma_f32_16x16x32_bf16(hf, wfr[s], acc, 0, 0, 0);
        }
        red[wid][lane] = acc;
        __syncthreads();

        // ---- gate math (256 threads: one per (batch, unit)) ----
        if (tid < 256) {
            const int li = (eb >> 2) * 16 + eu, j = eb & 3;
            float gt[4];
#pragma unroll
            for (int gg = 0; gg < 4; ++gg)
                gt[gg] = ((const float*)&red[gg][li])[j]
                       + ((const float*)&red[4 + gg][li])[j]
                       + xpre[gg];
            float si = 1.f / (1.f + expf(-gt[0]));
            float sf = 1.f / (1.f + expf(-gt[1]));
            float so = 1.f / (1.f + expf(-gt[3]));
            c_reg = sf * c_reg + si * tanhf(gt[2]);
            hout[eb][eu] = f2b(so * tanhf(c_reg));
        }
        __syncthreads();

        // ---- coherent h write to LLC (wave 0: 64 x u64) ----
        if (tid < 64) {
            int r = tid >> 2, c4 = (tid & 3) * 4;
            u64 v = *(const u64*)&hout[r][c4];
            __hip_atomic_store((u64*)(y + (size_t)(t * 16 + r) * DH + u0 + c4), v,
                               __ATOMIC_RELAXED, __HIP_MEMORY_SCOPE_AGENT);
        }

        if (t < 63) {
            __syncthreads();   // wave 0 drains its vmcnt before barrier
            if (tid == 0)
                __hip_atomic_store(bar + blockIdx.x * 32, (unsigned)(t + 1),
                                   __ATOMIC_RELAXED, __HIP_MEMORY_SCOPE_AGENT);
        }
    }
}

// ---------------------------------------------------------------------------
// Prior: softmax over 8 experts of out2(1024x1024 bf16) @ prior_W^T(8x1024)
// ---------------------------------------------------------------------------
__global__ __launch_bounds__(256)
void k_prior(const u16* __restrict__ out2, const float* __restrict__ pW,
             float* __restrict__ prior)
{
    const int n = blockIdx.x;
    const int tid = threadIdx.x;
    const int e = tid >> 5, lane = tid & 31;
    const u16* x = out2 + (size_t)n * 1024;
    const float* w = pW + (size_t)e * 1024;
    float s = 0.f;
    for (int k = lane; k < 1024; k += 32) s += b2f(x[k]) * w[k];
#pragma unroll
    for (int o = 16; o; o >>= 1) s += __shfl_down(s, o, 32);
    __shared__ float es[8];
    if (lane == 0) es[e] = s;
    __syncthreads();
    if (tid == 0) {
        float m = -1e30f;
        for (int i = 0; i < 8; ++i) m = fmaxf(m, es[i]);
        float Z = 0.f, ex[8];
        for (int i = 0; i < 8; ++i) { ex[i] = expf(es[i] - m); Z += ex[i]; }
        for (int i = 0; i < 8; ++i) prior[(size_t)n * 8 + i] = ex[i] / Z;
    }
}

// ---------------------------------------------------------------------------
// Combine: out[n0+nl][2v..2v+1] = log( sum_e pe[nl*8+e][.] * w_e + 1e-8 )
// 2 outputs per thread (u32 pe reads, float2 writes). Block 128, grid
// (125, nPer): v2 = bx*128+tid in [0,16000).
// ---------------------------------------------------------------------------
__global__ __launch_bounds__(128)
void k_combine(const u16* __restrict__ pe, const float* __restrict__ prior,
               const float* __restrict__ rsum, float* __restrict__ out, int n0)
{
    const int v2 = blockIdx.x * 128 + threadIdx.x;
    const int nl = blockIdx.y;
    __shared__ float w[8];
    if (threadIdx.x < 8)
        w[threadIdx.x] = prior[(size_t)(n0 + nl) * 8 + threadIdx.x]
                       / rsum[nl * 8 + threadIdx.x];
    __syncthreads();
    float a0 = 0.f, a1 = 0.f;
#pragma unroll
    for (int e = 0; e < 8; ++e) {
        unsigned pv = *(const unsigned*)&pe[(size_t)(nl * 8 + e) * 32000 + v2 * 2];
        a0 += b2f((u16)(pv & 0xffff)) * w[e];
        a1 += b2f((u16)(pv >> 16)) * w[e];
    }
    float2 o;
    o.x = logf(a0 + 1e-8f);
    o.y = logf(a1 + 1e-8f);
    *(float2*)&out[(size_t)(n0 + nl) * 32000 + v2 * 2] = o;
}

// ---------------------------------------------------------------------------
extern "C" void kernel_launch(void* const* d_in, const int* in_sizes, int n_in,
                              void* d_out, int out_size, void* d_ws, size_t ws_size,
                              hipStream_t stream)
{
    const int*   tok  = (const int*)d_in[0];
    const float* h0   = (const float*)d_in[1];
    const float* c0   = (const float*)d_in[2];
    const float* h1   = (const float*)d_in[3];
    const float* c1   = (const float*)d_in[4];
    const float* h2   = (const float*)d_in[5];
    const float* c2   = (const float*)d_in[6];
    const float* emb  = (const float*)d_in[7];
    const float* Wih0 = (const float*)d_in[8];
    const float* Whh0 = (const float*)d_in[9];
    const float* b0   = (const float*)d_in[10];
    const float* Wih1 = (const float*)d_in[11];
    const float* Whh1 = (const float*)d_in[12];
    const float* b1   = (const float*)d_in[13];
    const float* Wih2 = (const float*)d_in[14];
    const float* Whh2 = (const float*)d_in[15];
    const float* b2   = (const float*)d_in[16];
    const float* priW = (const float*)d_in[17];
    const float* latW = (const float*)d_in[18];
    const float* latb = (const float*)d_in[19];
    const float* decW = (const float*)d_in[20];
    const float* decb = (const float*)d_in[21];
    const float* gain = (const float*)d_in[22];

    // bump allocator (256B aligned)
    char* p = (char*)d_ws;
    auto alloc = [&](size_t bytes) {
        char* r = p; p += (bytes + 255) & ~(size_t)255; return r;
    };
    // ---- persistent region ----
    u16* Whh0b = (u16*)alloc(6144ull * 1536 * 2);
    u16* Whh1b = (u16*)alloc(6144ull * 1536 * 2);
    u16* Whh2b = (u16*)alloc(4096ull * 1024 * 2);
    u16* latWb = (u16*)alloc(4096ull * 1024 * 2);
    u16* decWb = (u16*)alloc(32000ull * 512 * 2);
    u16* latb16 = (u16*)alloc(8192ull * 512 * 2);
    float* pri   = (float*)alloc(8192 * 4);
    float* rowsum = (float*)alloc(8192 * 4);      // one slot per expert-row
    u16* out2 = (u16*)alloc(1024ull * 1024 * 2);
    unsigned* bars = (unsigned*)alloc(3 * 96 * 32 * 4);  // 3 layers x 96 slots
    // ---- transient region (dead before decoder; pe aliases it) ----
    char* trans = p;
    u16* Wih0b = (u16*)alloc(6144ull * 512 * 2);
    u16* Wih1b = (u16*)alloc(6144ull * 1536 * 2);
    u16* Wih2b = (u16*)alloc(4096ull * 1536 * 2);
    u16* x0 = (u16*)alloc(1024ull * 512 * 2);
    u16* x1 = (u16*)alloc(1024ull * 1536 * 2);
    u16* x2 = (u16*)alloc(1024ull * 1536 * 2);
    float* xg = (float*)alloc(1024ull * 6144 * 4);
    u16* pe = (u16*)trans;
    size_t cap = ws_size - (size_t)(trans - (char*)d_ws);
    int chunkRows = 128;
    if (cap >= 1024ull * 32000 * 2) chunkRows = 1024;
    else if (cap >= 512ull * 32000 * 2) chunkRows = 512;
    else if (cap >= 256ull * 32000 * 2) chunkRows = 256;
    int nPer = chunkRows / 8;

    // zero flag slots + rowsum (once; chunks use disjoint slices)
    hipMemsetAsync(bars, 0, 3 * 96 * 32 * 4, stream);
    hipMemsetAsync(rowsum, 0, 8192 * 4, stream);

    // weight conversions + embedding
    k_f2b<<<9216, 256, 0, stream>>>(Whh0, Whh0b, 2359296);
    k_f2b<<<9216, 256, 0, stream>>>(Whh1, Whh1b, 2359296);
    k_f2b<<<4096, 256, 0, stream>>>(Whh2, Whh2b, 1048576);
    k_f2b<<<3072, 256, 0, stream>>>(Wih0, Wih0b, 786432);
    k_f2b<<<9216, 256, 0, stream>>>(Wih1, Wih1b, 2359296);
    k_f2b<<<6144, 256, 0, stream>>>(Wih2, Wih2b, 1572864);
    k_f2b<<<4096, 256, 0, stream>>>(latW, latWb, 1048576);
    k_f2b<<<16000, 256, 0, stream>>>(decW, decWb, 4096000);
    k_embed<<<512, 256, 0, stream>>>(tok, emb, x0);

    // ---- layer 0 (512 -> 1536) ----
    k_gemm<0, 1><<<dim3(48, 8), 256, 0, stream>>>(
        x0, Wih0b, b0, xg, 1024, 6144, 512, nullptr, nullptr);
    {
        unsigned* bar = bars;
        int nb = 96;
        void* args[] = {(void*)&xg, (void*)&Whh0b, (void*)&h0, (void*)&c0,
                        (void*)&x1, (void*)&bar, (void*)&nb};
        hipLaunchCooperativeKernel(reinterpret_cast<void*>(&k_rnn<1536>),
                                   dim3(96), dim3(512), args, 0, stream);
    }

    // ---- layer 1 (1536 -> 1536) ----
    k_gemm<0, 1><<<dim3(48, 8), 256, 0, stream>>>(
        x1, Wih1b, b1, xg, 1024, 6144, 1536, nullptr, nullptr);
    {
        unsigned* bar = bars + 96 * 32;
        int nb = 96;
        void* args[] = {(void*)&xg, (void*)&Whh1b, (void*)&h1, (void*)&c1,
                        (void*)&x2, (void*)&bar, (void*)&nb};
        hipLaunchCooperativeKernel(reinterpret_cast<void*>(&k_rnn<1536>),
                                   dim3(96), dim3(512), args, 0, stream);
    }

    // ---- layer 2 (1536 -> 1024) ----
    k_gemm<0, 1><<<dim3(32, 8), 256, 0, stream>>>(
        x2, Wih2b, b2, xg, 1024, 4096, 1536, nullptr, nullptr);
    {
        unsigned* bar = bars + 2 * 96 * 32;
        int nb = 64;
        void* args[] = {(void*)&xg, (void*)&Whh2b, (void*)&h2, (void*)&c2,
                        (void*)&out2, (void*)&bar, (void*)&nb};
        hipLaunchCooperativeKernel(reinterpret_cast<void*>(&k_rnn<1024>),
                                   dim3(64), dim3(512), args, 0, stream);
    }

    // ---- MoS head ----
    k_prior<<<1024, 256, 0, stream>>>(out2, priW, pri);
    k_gemm<1, 1><<<dim3(32, 8), 256, 0, stream>>>(
        out2, latWb, latb, latb16, 1024, 4096, 1024, gain, nullptr);

    // ---- decoder, chunked (pe aliases dead transient region) ----
    for (int nb = 0; nb < 1024; nb += nPer) {
        const u16* Ach = latb16 + (size_t)nb * 8 * 512;
        float* rsumc = rowsum + (size_t)nb * 8;
        if (chunkRows >= 256) {
            k_gemm_dec2<<<dim3(125, chunkRows / 256), 512, 0, stream>>>(
                Ach, decWb, decb, pe, chunkRows, 32000, 512, rsumc);
        } else {
            k_gemm<2, 1><<<dim3(250, chunkRows / 128), 256, 0, stream>>>(
                Ach, decWb, decb, pe, chunkRows, 32000, 512, nullptr, rsumc);
        }
        k_combine<<<dim3(125, nPer), 128, 0, stream>>>(
            pe, pri, rowsum + nb * 8, (float*)d_out, nb);
    }
}

// Round 11
// 1425.607 us; speedup vs baseline: 1.0944x; 1.0944x over previous
//
#include <hip/hip_runtime.h>
#include <hip/hip_bf16.h>

typedef __attribute__((ext_vector_type(8))) short short8;
typedef __attribute__((ext_vector_type(4))) float f32x4;
typedef unsigned short u16;
typedef unsigned long long u64;

__device__ __forceinline__ u16 f2b(float f) {
    unsigned u = __float_as_uint(f);
    return (u16)((u + 0x7FFFu + ((u >> 16) & 1u)) >> 16);
}
__device__ __forceinline__ float b2f(u16 u) {
    return __uint_as_float(((unsigned)u) << 16);
}
__device__ __forceinline__ void gload16(const void* g, void* l) {
    __builtin_amdgcn_global_load_lds(
        (const __attribute__((address_space(1))) void*)g,
        (__attribute__((address_space(3))) void*)l, 16, 0, 0);
}

// Conversion jobs carried by layer-0 k_rnn's helper blocks.
struct CvtJobs {
    const float* s[6];
    u16* d[6];
    int n4[6];
    int njobs;
};

// ---------------------------------------------------------------------------
// f32 -> bf16 bulk convert (only for pre-RNN weights: Whh0, Wih0)
// ---------------------------------------------------------------------------
__global__ __launch_bounds__(256)
void k_f2b(const float* __restrict__ s, u16* __restrict__ d, int n4)
{
    int i = blockIdx.x * 256 + threadIdx.x;
    if (i >= n4) return;
    float4 v = ((const float4*)s)[i];
    short4 o;
    o.x = (short)f2b(v.x); o.y = (short)f2b(v.y);
    o.z = (short)f2b(v.z); o.w = (short)f2b(v.w);
    ((short4*)d)[i] = o;
}

// ---------------------------------------------------------------------------
// Embedding gather -> bf16
// ---------------------------------------------------------------------------
__global__ __launch_bounds__(256)
void k_embed(const int* __restrict__ tok, const float* __restrict__ emb,
             u16* __restrict__ x0)
{
    int i = blockIdx.x * 256 + threadIdx.x;   // 131072: 4 elems each
    int n = i >> 7, p4 = i & 127;
    float4 v = ((const float4*)(emb + (size_t)tok[n] * 512))[p4];
    short4 o;
    o.x = (short)f2b(v.x); o.y = (short)f2b(v.y);
    o.z = (short)f2b(v.z); o.w = (short)f2b(v.w);
    ((short4*)x0)[i] = o;
}

// ---------------------------------------------------------------------------
// MFMA bf16 GEMM, 128x128 tile, 4 waves (2x2), K-step 32, linear LDS,
// DOUBLE-BUFFERED: stage(t+1) issued before frag-reads+MFMA of tile t,
// ONE barrier per tile (T3 minimum-2-phase recipe).
// EPI=0: C f32. EPI=1: latent head -> bf16, remap (e,p), tanh*gain.
// EPI=2: decoder: store bf16 exp(min(v,80)); atomicAdd per-row sums to rsum.
// ---------------------------------------------------------------------------
template <int EPI>
__global__ __launch_bounds__(256)
void k_gemm(const u16* __restrict__ A, const u16* __restrict__ B,
            const float* __restrict__ bias, void* __restrict__ Cp,
            int M, int N, int K, const float* __restrict__ gain,
            float* __restrict__ rsum)
{
    __shared__ __align__(16) u16 As[2][128 * 32];
    __shared__ __align__(16) u16 Bs[2][128 * 32];
    __shared__ float rs[2][128];
    const int tid = threadIdx.x;
    const int lane = tid & 63, wid = tid >> 6;
    const int wr = wid >> 1, wc = wid & 1;
    const int l15 = lane & 15, l4 = lane >> 4;
    const int row0 = blockIdx.y * 128, col0 = blockIdx.x * 128;

    const int srA = wid * 16 + (lane >> 2);
    const int skA = (lane & 3) * 8;

    auto stage = [&](int buf, int k0) {
        gload16(A + (size_t)(row0 + srA) * K + k0 + skA, &As[buf][wid * 512]);
        gload16(A + (size_t)(row0 + 64 + srA) * K + k0 + skA, &As[buf][2048 + wid * 512]);
        gload16(B + (size_t)(col0 + srA) * K + k0 + skA, &Bs[buf][wid * 512]);
        gload16(B + (size_t)(col0 + 64 + srA) * K + k0 + skA, &Bs[buf][2048 + wid * 512]);
    };

    f32x4 acc[4][4] = {};

    stage(0, 0);
    __syncthreads();
    int cur = 0;
    for (int k0 = 0; k0 < K; k0 += 32) {
        if (k0 + 32 < K) stage(cur ^ 1, k0 + 32);

        short8 af[4], bfv[4];
#pragma unroll
        for (int i = 0; i < 4; ++i)
            af[i]  = *(const short8*)&As[cur][(wr * 64 + i * 16 + l15) * 32 + l4 * 8];
#pragma unroll
        for (int i = 0; i < 4; ++i)
            bfv[i] = *(const short8*)&Bs[cur][(wc * 64 + i * 16 + l15) * 32 + l4 * 8];
#pragma unroll
        for (int mi = 0; mi < 4; ++mi)
#pragma unroll
            for (int ni = 0; ni < 4; ++ni)
                acc[mi][ni] = __builtin_amdgcn_mfma_f32_16x16x32_bf16(
                    af[mi], bfv[ni], acc[mi][ni], 0, 0, 0);
        __syncthreads();
        cur ^= 1;
    }

    if (EPI == 2) {
#pragma unroll
        for (int mi = 0; mi < 4; ++mi) {
#pragma unroll
            for (int j = 0; j < 4; ++j) {
                int rb = row0 + wr * 64 + mi * 16 + l4 * 4 + j;
                float rsub = 0.f;
#pragma unroll
                for (int ni = 0; ni < 4; ++ni) {
                    int cc = col0 + wc * 64 + ni * 16 + l15;
                    float pv = expf(fminf(acc[mi][ni][j] + bias[cc], 80.f));
                    ((u16*)Cp)[(size_t)rb * N + cc] = f2b(pv);
                    rsub += pv;
                }
#pragma unroll
                for (int o = 1; o < 16; o <<= 1) rsub += __shfl_xor(rsub, o, 64);
                if (l15 == 0)
                    rs[wc][wr * 64 + mi * 16 + l4 * 4 + j] = rsub;
            }
        }
        __syncthreads();
        if (tid < 128)
            atomicAdd(&rsum[row0 + tid], rs[0][tid] + rs[1][tid]);
        return;
    }

#pragma unroll
    for (int mi = 0; mi < 4; ++mi) {
#pragma unroll
        for (int ni = 0; ni < 4; ++ni) {
            int rb = row0 + wr * 64 + mi * 16 + l4 * 4;
            int cc = col0 + wc * 64 + ni * 16 + l15;
            float bv = bias[cc];
#pragma unroll
            for (int j = 0; j < 4; ++j) {
                float v = acc[mi][ni][j] + bv;
                if (EPI == 0) {
                    ((float*)Cp)[(size_t)(rb + j) * N + cc] = v;
                } else {
                    int e = cc >> 9, pp = cc & 511;
                    ((u16*)Cp)[(((size_t)(rb + j) * 8 + e) << 9) | pp] =
                        f2b(tanhf(v) * gain[pp]);
                }
            }
        }
    }
}

// ---------------------------------------------------------------------------
// Decoder GEMM, 256x128 tile (round-9 winner), 512 threads (8 waves, 4x2),
// DOUBLE-BUFFERED staging (one barrier per K-tile).
// pe[r][v] = bf16(exp(min(logit,80))), rowsum[row0+r] += partials.
// ---------------------------------------------------------------------------
__global__ __launch_bounds__(512)
void k_gemm_dec(const u16* __restrict__ A, const u16* __restrict__ B,
                const float* __restrict__ bias, u16* __restrict__ pe,
                int M, int N, int K, float* __restrict__ rsum)
{
    __shared__ __align__(16) u16 As[2][256 * 32];
    __shared__ __align__(16) u16 Bs[2][128 * 32];
    __shared__ float rs[2][256];
    const int tid = threadIdx.x;
    const int lane = tid & 63, wid = tid >> 6;
    const int wr = wid >> 1, wc = wid & 1;
    const int l15 = lane & 15, l4 = lane >> 4;
    const int row0 = blockIdx.y * 256, col0 = blockIdx.x * 128;

    const int srA = wid * 16 + (lane >> 2);    // 0..127
    const int skA = (lane & 3) * 8;

    auto stage = [&](int buf, int k0) {
        gload16(A + (size_t)(row0 + srA) * K + k0 + skA, &As[buf][wid * 512]);
        gload16(A + (size_t)(row0 + 128 + srA) * K + k0 + skA, &As[buf][4096 + wid * 512]);
        gload16(B + (size_t)(col0 + srA) * K + k0 + skA, &Bs[buf][wid * 512]);
    };

    f32x4 acc[4][4] = {};

    stage(0, 0);
    __syncthreads();
    int cur = 0;
    for (int k0 = 0; k0 < K; k0 += 32) {
        if (k0 + 32 < K) stage(cur ^ 1, k0 + 32);

        short8 af[4], bfv[4];
#pragma unroll
        for (int i = 0; i < 4; ++i)
            af[i]  = *(const short8*)&As[cur][(wr * 64 + i * 16 + l15) * 32 + l4 * 8];
#pragma unroll
        for (int i = 0; i < 4; ++i)
            bfv[i] = *(const short8*)&Bs[cur][(wc * 64 + i * 16 + l15) * 32 + l4 * 8];
#pragma unroll
        for (int mi = 0; mi < 4; ++mi)
#pragma unroll
            for (int ni = 0; ni < 4; ++ni)
                acc[mi][ni] = __builtin_amdgcn_mfma_f32_16x16x32_bf16(
                    af[mi], bfv[ni], acc[mi][ni], 0, 0, 0);
        __syncthreads();
        cur ^= 1;
    }

#pragma unroll
    for (int mi = 0; mi < 4; ++mi) {
#pragma unroll
        for (int j = 0; j < 4; ++j) {
            int rloc = wr * 64 + mi * 16 + l4 * 4 + j;
            float rsub = 0.f;
#pragma unroll
            for (int ni = 0; ni < 4; ++ni) {
                int cc = col0 + wc * 64 + ni * 16 + l15;
                float pv = expf(fminf(acc[mi][ni][j] + bias[cc], 80.f));
                pe[(size_t)(row0 + rloc) * N + cc] = f2b(pv);
                rsub += pv;
            }
#pragma unroll
            for (int o = 1; o < 16; o <<= 1) rsub += __shfl_xor(rsub, o, 64);
            if (l15 == 0) rs[wc][rloc] = rsub;
        }
    }
    __syncthreads();
    if (tid < 256)
        atomicAdd(&rsum[row0 + tid], rs[0][tid] + rs[1][tid]);
}

// ---------------------------------------------------------------------------
// Persistent-weight cooperative LSTM layer, FENCELESS protocol (round-7
// proven, worker path byte-identical). Blocks >= nb are CONVERSION HELPERS:
// they grid-stride f2b the CvtJobs list and exit (layer 0 only) — the RNN
// is latency-bound on 96 CUs, so the other 160 CUs convert decW/latW/
// Wih1/2/Whh1/2 in its shadow. Stream order makes the conversions complete
// before their consumers (kernel ends when ALL blocks end).
// ---------------------------------------------------------------------------
template <int DH>
__global__ void __launch_bounds__(512)
k_rnn(const float* __restrict__ xg,    // (1024, 4*DH) f32
      const u16* __restrict__ W,       // (4*DH, DH) bf16
      const float* __restrict__ h0f,   // (16, DH) f32
      const float* __restrict__ c0f,   // (16, DH) f32
      u16* __restrict__ y,             // (1024, DH) bf16
      unsigned* __restrict__ bar,      // nb slots, stride 32 uints, zeroed
      int nb, CvtJobs jobs)
{
    if ((int)blockIdx.x >= nb) {
        const int hb = blockIdx.x - nb, nh = gridDim.x - nb;
        for (int j = 0; j < jobs.njobs; ++j) {
            const float4* s = (const float4*)jobs.s[j];
            short4* d = (short4*)jobs.d[j];
            const int n4 = jobs.n4[j];
            for (int i = hb * 512 + threadIdx.x; i < n4; i += nh * 512) {
                float4 v = s[i];
                short4 o;
                o.x = (short)f2b(v.x); o.y = (short)f2b(v.y);
                o.z = (short)f2b(v.z); o.w = (short)f2b(v.w);
                d[i] = o;
            }
        }
        return;
    }

    constexpr int DH2 = DH / 2;
    constexpr int NSH = DH2 / 32;      // MFMA k-steps per K-half
    constexpr int NL  = 16 * DH / 4 / 512;   // u64 h-loads per thread
    constexpr int RW  = DH / 4;        // u64 per h row
    constexpr int LDH = DH + 8;        // pad -> 2-way banks (free)
    __shared__ __align__(16) u16 hs[16][LDH];
    __shared__ __align__(16) f32x4 red[8][64];
    __shared__ __align__(16) u16 hout[16][16];

    const int tid = threadIdx.x;
    const int lane = tid & 63, wid = tid >> 6;
    const int g = wid & 3, kh = wid >> 2;
    const int l15 = lane & 15, l4 = lane >> 4;
    const int u0 = blockIdx.x * 16;

    // ---- load W fragments into registers (once) ----
    short8 wfr[NSH];
    {
        const u16* wa = W + (size_t)(g * DH + u0 + l15) * DH + kh * DH2 + l4 * 8;
#pragma unroll
        for (int s = 0; s < NSH; ++s) wfr[s] = *(const short8*)(wa + s * 32);
    }

    const int eb = tid >> 4, eu = tid & 15;      // epilogue mapping (tid<256)
    float c_reg = (tid < 256) ? c0f[(size_t)eb * DH + u0 + eu] : 0.f;

    for (int t = 0; t < 64; ++t) {
        // ---- prefetch xg row into regs ----
        float xpre[4];
        if (tid < 256) {
            const float* xr = xg + (size_t)(t * 16 + eb) * 4 * DH + u0 + eu;
#pragma unroll
            for (int gg = 0; gg < 4; ++gg) xpre[gg] = xr[(size_t)gg * DH];
        }

        // ---- wait for producers + stage h_{t-1} into LDS ----
        if (t == 0) {
            for (int i = tid; i < 16 * DH / 4; i += 512) {
                int r = i / (DH / 4), k4 = i % (DH / 4);
                float4 v = *(const float4*)(h0f + (size_t)r * DH + k4 * 4);
                short4 o;
                o.x = (short)f2b(v.x); o.y = (short)f2b(v.y);
                o.z = (short)f2b(v.z); o.w = (short)f2b(v.w);
                *(short4*)&hs[r][k4 * 4] = o;
            }
            __syncthreads();
        } else {
            if (tid < nb) {
                while (__hip_atomic_load(bar + tid * 32, __ATOMIC_RELAXED,
                                         __HIP_MEMORY_SCOPE_AGENT) < (unsigned)t)
                    __builtin_amdgcn_s_sleep(1);
            }
            __syncthreads();
            // coherent h read from LLC (batched -> pipelined loads)
            const u64* hp = (const u64*)(y + (size_t)(t - 1) * 16 * DH);
            u64 tmp[NL];
#pragma unroll
            for (int j = 0; j < NL; ++j)
                tmp[j] = __hip_atomic_load(hp + tid + j * 512, __ATOMIC_RELAXED,
                                           __HIP_MEMORY_SCOPE_AGENT);
#pragma unroll
            for (int j = 0; j < NL; ++j) {
                int idx = tid + j * 512;
                int r = idx / RW, c = (idx % RW) * 4;
                *(u64*)&hs[r][c] = tmp[j];
            }
            __syncthreads();
        }

        // ---- MFMA from register-resident W ----
        f32x4 acc = {};
#pragma unroll
        for (int s = 0; s < NSH; ++s) {
            short8 hf = *(const short8*)&hs[l15][kh * DH2 + s * 32 + l4 * 8];
            acc = __builtin_amdgcn_mfma_f32_16x16x32_bf16(hf, wfr[s], acc, 0, 0, 0);
        }
        red[wid][lane] = acc;
        __syncthreads();

        // ---- gate math (256 threads: one per (batch, unit)) ----
        if (tid < 256) {
            const int li = (eb >> 2) * 16 + eu, j = eb & 3;
            float gt[4];
#pragma unroll
            for (int gg = 0; gg < 4; ++gg)
                gt[gg] = ((const float*)&red[gg][li])[j]
                       + ((const float*)&red[4 + gg][li])[j]
                       + xpre[gg];
            float si = 1.f / (1.f + expf(-gt[0]));
            float sf = 1.f / (1.f + expf(-gt[1]));
            float so = 1.f / (1.f + expf(-gt[3]));
            c_reg = sf * c_reg + si * tanhf(gt[2]);
            hout[eb][eu] = f2b(so * tanhf(c_reg));
        }
        __syncthreads();

        // ---- coherent h write to LLC (wave 0: 64 x u64) ----
        if (tid < 64) {
            int r = tid >> 2, c4 = (tid & 3) * 4;
            u64 v = *(const u64*)&hout[r][c4];
            __hip_atomic_store((u64*)(y + (size_t)(t * 16 + r) * DH + u0 + c4), v,
                               __ATOMIC_RELAXED, __HIP_MEMORY_SCOPE_AGENT);
        }

        if (t < 63) {
            __syncthreads();   // wave 0 drains its vmcnt before barrier
            if (tid == 0)
                __hip_atomic_store(bar + blockIdx.x * 32, (unsigned)(t + 1),
                                   __ATOMIC_RELAXED, __HIP_MEMORY_SCOPE_AGENT);
        }
    }
}

// ---------------------------------------------------------------------------
// Prior: softmax over 8 experts of out2(1024x1024 bf16) @ prior_W^T(8x1024)
// ---------------------------------------------------------------------------
__global__ __launch_bounds__(256)
void k_prior(const u16* __restrict__ out2, const float* __restrict__ pW,
             float* __restrict__ prior)
{
    const int n = blockIdx.x;
    const int tid = threadIdx.x;
    const int e = tid >> 5, lane = tid & 31;
    const u16* x = out2 + (size_t)n * 1024;
    const float* w = pW + (size_t)e * 1024;
    float s = 0.f;
    for (int k = lane; k < 1024; k += 32) s += b2f(x[k]) * w[k];
#pragma unroll
    for (int o = 16; o; o >>= 1) s += __shfl_down(s, o, 32);
    __shared__ float es[8];
    if (lane == 0) es[e] = s;
    __syncthreads();
    if (tid == 0) {
        float m = -1e30f;
        for (int i = 0; i < 8; ++i) m = fmaxf(m, es[i]);
        float Z = 0.f, ex[8];
        for (int i = 0; i < 8; ++i) { ex[i] = expf(es[i] - m); Z += ex[i]; }
        for (int i = 0; i < 8; ++i) prior[(size_t)n * 8 + i] = ex[i] / Z;
    }
}

// ---------------------------------------------------------------------------
// Combine: out[n0+nl][2v..2v+1] = log( sum_e pe[nl*8+e][.] * w_e + 1e-8 )
// 2 outputs per thread (u32 pe reads, float2 writes).
// ---------------------------------------------------------------------------
__global__ __launch_bounds__(128)
void k_combine(const u16* __restrict__ pe, const float* __restrict__ prior,
               const float* __restrict__ rsum, float* __restrict__ out, int n0)
{
    const int v2 = blockIdx.x * 128 + threadIdx.x;
    const int nl = blockIdx.y;
    __shared__ float w[8];
    if (threadIdx.x < 8)
        w[threadIdx.x] = prior[(size_t)(n0 + nl) * 8 + threadIdx.x]
                       / rsum[nl * 8 + threadIdx.x];
    __syncthreads();
    float a0 = 0.f, a1 = 0.f;
#pragma unroll
    for (int e = 0; e < 8; ++e) {
        unsigned pv = *(const unsigned*)&pe[(size_t)(nl * 8 + e) * 32000 + v2 * 2];
        a0 += b2f((u16)(pv & 0xffff)) * w[e];
        a1 += b2f((u16)(pv >> 16)) * w[e];
    }
    float2 o;
    o.x = logf(a0 + 1e-8f);
    o.y = logf(a1 + 1e-8f);
    *(float2*)&out[(size_t)(n0 + nl) * 32000 + v2 * 2] = o;
}

// ---------------------------------------------------------------------------
extern "C" void kernel_launch(void* const* d_in, const int* in_sizes, int n_in,
                              void* d_out, int out_size, void* d_ws, size_t ws_size,
                              hipStream_t stream)
{
    const int*   tok  = (const int*)d_in[0];
    const float* h0   = (const float*)d_in[1];
    const float* c0   = (const float*)d_in[2];
    const float* h1   = (const float*)d_in[3];
    const float* c1   = (const float*)d_in[4];
    const float* h2   = (const float*)d_in[5];
    const float* c2   = (const float*)d_in[6];
    const float* emb  = (const float*)d_in[7];
    const float* Wih0 = (const float*)d_in[8];
    const float* Whh0 = (const float*)d_in[9];
    const float* b0   = (const float*)d_in[10];
    const float* Wih1 = (const float*)d_in[11];
    const float* Whh1 = (const float*)d_in[12];
    const float* b1   = (const float*)d_in[13];
    const float* Wih2 = (const float*)d_in[14];
    const float* Whh2 = (const float*)d_in[15];
    const float* b2   = (const float*)d_in[16];
    const float* priW = (const float*)d_in[17];
    const float* latW = (const float*)d_in[18];
    const float* latb = (const float*)d_in[19];
    const float* decW = (const float*)d_in[20];
    const float* decb = (const float*)d_in[21];
    const float* gain = (const float*)d_in[22];

    // bump allocator (256B aligned)
    char* p = (char*)d_ws;
    auto alloc = [&](size_t bytes) {
        char* r = p; p += (bytes + 255) & ~(size_t)255; return r;
    };
    // ---- persistent region ----
    u16* Whh0b = (u16*)alloc(6144ull * 1536 * 2);
    u16* Whh1b = (u16*)alloc(6144ull * 1536 * 2);
    u16* Whh2b = (u16*)alloc(4096ull * 1024 * 2);
    u16* latWb = (u16*)alloc(4096ull * 1024 * 2);
    u16* decWb = (u16*)alloc(32000ull * 512 * 2);
    u16* latb16 = (u16*)alloc(8192ull * 512 * 2);
    float* pri   = (float*)alloc(8192 * 4);
    float* rowsum = (float*)alloc(8192 * 4);      // one slot per expert-row
    u16* out2 = (u16*)alloc(1024ull * 1024 * 2);
    unsigned* bars = (unsigned*)alloc(3 * 96 * 32 * 4);  // 3 layers x 96 slots
    // ---- transient region (dead before decoder; pe aliases it) ----
    char* trans = p;
    u16* Wih0b = (u16*)alloc(6144ull * 512 * 2);
    u16* Wih1b = (u16*)alloc(6144ull * 1536 * 2);
    u16* Wih2b = (u16*)alloc(4096ull * 1536 * 2);
    u16* x0 = (u16*)alloc(1024ull * 512 * 2);
    u16* x1 = (u16*)alloc(1024ull * 1536 * 2);
    u16* x2 = (u16*)alloc(1024ull * 1536 * 2);
    float* xg = (float*)alloc(1024ull * 6144 * 4);
    u16* pe = (u16*)trans;
    size_t cap = ws_size - (size_t)(trans - (char*)d_ws);
    int chunkRows = 128;
    if (cap >= 1024ull * 32000 * 2) chunkRows = 1024;
    else if (cap >= 512ull * 32000 * 2) chunkRows = 512;
    else if (cap >= 256ull * 32000 * 2) chunkRows = 256;
    int nPer = chunkRows / 8;

    // zero flag slots + rowsum (once; chunks use disjoint slices)
    hipMemsetAsync(bars, 0, 3 * 96 * 32 * 4, stream);
    hipMemsetAsync(rowsum, 0, 8192 * 4, stream);

    // pre-RNN conversions + embedding (only what layer 0 needs)
    k_f2b<<<9216, 256, 0, stream>>>(Whh0, Whh0b, 2359296);
    k_f2b<<<3072, 256, 0, stream>>>(Wih0, Wih0b, 786432);
    k_embed<<<512, 256, 0, stream>>>(tok, emb, x0);

    // ---- layer 0 (512 -> 1536) ----
    k_gemm<0><<<dim3(48, 8), 256, 0, stream>>>(
        x0, Wih0b, b0, xg, 1024, 6144, 512, nullptr, nullptr);
    {
        unsigned* bar = bars;
        int nb = 96;
        CvtJobs jobs;
        jobs.s[0] = Whh1; jobs.d[0] = Whh1b; jobs.n4[0] = 2359296;
        jobs.s[1] = Whh2; jobs.d[1] = Whh2b; jobs.n4[1] = 1048576;
        jobs.s[2] = Wih1; jobs.d[2] = Wih1b; jobs.n4[2] = 2359296;
        jobs.s[3] = Wih2; jobs.d[3] = Wih2b; jobs.n4[3] = 1572864;
        jobs.s[4] = latW; jobs.d[4] = latWb; jobs.n4[4] = 1048576;
        jobs.s[5] = decW; jobs.d[5] = decWb; jobs.n4[5] = 4096000;
        jobs.njobs = 6;
        void* args[] = {(void*)&xg, (void*)&Whh0b, (void*)&h0, (void*)&c0,
                        (void*)&x1, (void*)&bar, (void*)&nb, (void*)&jobs};
        hipLaunchCooperativeKernel(reinterpret_cast<void*>(&k_rnn<1536>),
                                   dim3(256), dim3(512), args, 0, stream);
    }

    // ---- layer 1 (1536 -> 1536) ----
    k_gemm<0><<<dim3(48, 8), 256, 0, stream>>>(
        x1, Wih1b, b1, xg, 1024, 6144, 1536, nullptr, nullptr);
    {
        unsigned* bar = bars + 96 * 32;
        int nb = 96;
        CvtJobs jobs;
        jobs.njobs = 0;
        void* args[] = {(void*)&xg, (void*)&Whh1b, (void*)&h1, (void*)&c1,
                        (void*)&x2, (void*)&bar, (void*)&nb, (void*)&jobs};
        hipLaunchCooperativeKernel(reinterpret_cast<void*>(&k_rnn<1536>),
                                   dim3(96), dim3(512), args, 0, stream);
    }

    // ---- layer 2 (1536 -> 1024) ----
    k_gemm<0><<<dim3(32, 8), 256, 0, stream>>>(
        x2, Wih2b, b2, xg, 1024, 4096, 1536, nullptr, nullptr);
    {
        unsigned* bar = bars + 2 * 96 * 32;
        int nb = 64;
        CvtJobs jobs;
        jobs.njobs = 0;
        void* args[] = {(void*)&xg, (void*)&Whh2b, (void*)&h2, (void*)&c2,
                        (void*)&out2, (void*)&bar, (void*)&nb, (void*)&jobs};
        hipLaunchCooperativeKernel(reinterpret_cast<void*>(&k_rnn<1024>),
                                   dim3(64), dim3(512), args, 0, stream);
    }

    // ---- MoS head ----
    k_prior<<<1024, 256, 0, stream>>>(out2, priW, pri);
    k_gemm<1><<<dim3(32, 8), 256, 0, stream>>>(
        out2, latWb, latb, latb16, 1024, 4096, 1024, gain, nullptr);

    // ---- decoder, chunked (pe aliases dead transient region) ----
    for (int nb = 0; nb < 1024; nb += nPer) {
        const u16* Ach = latb16 + (size_t)nb * 8 * 512;
        float* rsumc = rowsum + (size_t)nb * 8;
        if (chunkRows >= 256) {
            k_gemm_dec<<<dim3(250, chunkRows / 256), 512, 0, stream>>>(
                Ach, decWb, decb, pe, chunkRows, 32000, 512, rsumc);
        } else {
            k_gemm<2><<<dim3(250, chunkRows / 128), 256, 0, stream>>>(
                Ach, decWb, decb, pe, chunkRows, 32000, 512, nullptr, rsumc);
        }
        k_combine<<<dim3(125, nPer), 128, 0, stream>>>(
            pe, pri, rowsum + nb * 8, (float*)d_out, nb);
    }
}

// Round 12
// 1421.040 us; speedup vs baseline: 1.0979x; 1.0032x over previous
//
#include <hip/hip_runtime.h>
#include <hip/hip_bf16.h>

typedef __attribute__((ext_vector_type(8))) short short8;
typedef __attribute__((ext_vector_type(4))) float f32x4;
typedef unsigned short u16;
typedef unsigned long long u64;

__device__ __forceinline__ u16 f2b(float f) {
    unsigned u = __float_as_uint(f);
    return (u16)((u + 0x7FFFu + ((u >> 16) & 1u)) >> 16);
}
__device__ __forceinline__ float b2f(u16 u) {
    return __uint_as_float(((unsigned)u) << 16);
}
__device__ __forceinline__ void gload16(const void* g, void* l) {
    __builtin_amdgcn_global_load_lds(
        (const __attribute__((address_space(1))) void*)g,
        (__attribute__((address_space(3))) void*)l, 16, 0, 0);
}

// Conversion jobs carried by layer-0 k_rnn's helper blocks.
struct CvtJobs {
    const float* s[6];
    u16* d[6];
    int n4[6];
    int njobs;
};

// ---------------------------------------------------------------------------
// f32 -> bf16 bulk convert (only for pre-RNN weights: Whh0, Wih0)
// ---------------------------------------------------------------------------
__global__ __launch_bounds__(256)
void k_f2b(const float* __restrict__ s, u16* __restrict__ d, int n4)
{
    int i = blockIdx.x * 256 + threadIdx.x;
    if (i >= n4) return;
    float4 v = ((const float4*)s)[i];
    short4 o;
    o.x = (short)f2b(v.x); o.y = (short)f2b(v.y);
    o.z = (short)f2b(v.z); o.w = (short)f2b(v.w);
    ((short4*)d)[i] = o;
}

// ---------------------------------------------------------------------------
// Embedding gather -> bf16
// ---------------------------------------------------------------------------
__global__ __launch_bounds__(256)
void k_embed(const int* __restrict__ tok, const float* __restrict__ emb,
             u16* __restrict__ x0)
{
    int i = blockIdx.x * 256 + threadIdx.x;   // 131072: 4 elems each
    int n = i >> 7, p4 = i & 127;
    float4 v = ((const float4*)(emb + (size_t)tok[n] * 512))[p4];
    short4 o;
    o.x = (short)f2b(v.x); o.y = (short)f2b(v.y);
    o.z = (short)f2b(v.z); o.w = (short)f2b(v.w);
    ((short4*)x0)[i] = o;
}

// ---------------------------------------------------------------------------
// MFMA bf16 GEMM, 128x128 tile, 4 waves (2x2), K-step 32, linear LDS,
// DOUBLE-BUFFERED: stage(t+1) issued before frag-reads+MFMA of tile t.
// EPI=0: C f32. EPI=1: latent head -> bf16, remap (e,p), tanh*gain.
// EPI=2: decoder fallback: bf16 exp + rowsum atomicAdd.
// ---------------------------------------------------------------------------
template <int EPI>
__global__ __launch_bounds__(256)
void k_gemm(const u16* __restrict__ A, const u16* __restrict__ B,
            const float* __restrict__ bias, void* __restrict__ Cp,
            int M, int N, int K, const float* __restrict__ gain,
            float* __restrict__ rsum)
{
    __shared__ __align__(16) u16 As[2][128 * 32];
    __shared__ __align__(16) u16 Bs[2][128 * 32];
    __shared__ float rs[2][128];
    const int tid = threadIdx.x;
    const int lane = tid & 63, wid = tid >> 6;
    const int wr = wid >> 1, wc = wid & 1;
    const int l15 = lane & 15, l4 = lane >> 4;
    const int row0 = blockIdx.y * 128, col0 = blockIdx.x * 128;

    const int srA = wid * 16 + (lane >> 2);
    const int skA = (lane & 3) * 8;

    auto stage = [&](int buf, int k0) {
        gload16(A + (size_t)(row0 + srA) * K + k0 + skA, &As[buf][wid * 512]);
        gload16(A + (size_t)(row0 + 64 + srA) * K + k0 + skA, &As[buf][2048 + wid * 512]);
        gload16(B + (size_t)(col0 + srA) * K + k0 + skA, &Bs[buf][wid * 512]);
        gload16(B + (size_t)(col0 + 64 + srA) * K + k0 + skA, &Bs[buf][2048 + wid * 512]);
    };

    f32x4 acc[4][4] = {};

    stage(0, 0);
    __syncthreads();
    int cur = 0;
    for (int k0 = 0; k0 < K; k0 += 32) {
        if (k0 + 32 < K) stage(cur ^ 1, k0 + 32);

        short8 af[4], bfv[4];
#pragma unroll
        for (int i = 0; i < 4; ++i)
            af[i]  = *(const short8*)&As[cur][(wr * 64 + i * 16 + l15) * 32 + l4 * 8];
#pragma unroll
        for (int i = 0; i < 4; ++i)
            bfv[i] = *(const short8*)&Bs[cur][(wc * 64 + i * 16 + l15) * 32 + l4 * 8];
#pragma unroll
        for (int mi = 0; mi < 4; ++mi)
#pragma unroll
            for (int ni = 0; ni < 4; ++ni)
                acc[mi][ni] = __builtin_amdgcn_mfma_f32_16x16x32_bf16(
                    af[mi], bfv[ni], acc[mi][ni], 0, 0, 0);
        __syncthreads();
        cur ^= 1;
    }

    if (EPI == 2) {
#pragma unroll
        for (int mi = 0; mi < 4; ++mi) {
#pragma unroll
            for (int j = 0; j < 4; ++j) {
                int rb = row0 + wr * 64 + mi * 16 + l4 * 4 + j;
                float rsub = 0.f;
#pragma unroll
                for (int ni = 0; ni < 4; ++ni) {
                    int cc = col0 + wc * 64 + ni * 16 + l15;
                    float pv = expf(fminf(acc[mi][ni][j] + bias[cc], 80.f));
                    ((u16*)Cp)[(size_t)rb * N + cc] = f2b(pv);
                    rsub += pv;
                }
#pragma unroll
                for (int o = 1; o < 16; o <<= 1) rsub += __shfl_xor(rsub, o, 64);
                if (l15 == 0)
                    rs[wc][wr * 64 + mi * 16 + l4 * 4 + j] = rsub;
            }
        }
        __syncthreads();
        if (tid < 128)
            atomicAdd(&rsum[row0 + tid], rs[0][tid] + rs[1][tid]);
        return;
    }

#pragma unroll
    for (int mi = 0; mi < 4; ++mi) {
#pragma unroll
        for (int ni = 0; ni < 4; ++ni) {
            int rb = row0 + wr * 64 + mi * 16 + l4 * 4;
            int cc = col0 + wc * 64 + ni * 16 + l15;
            float bv = bias[cc];
#pragma unroll
            for (int j = 0; j < 4; ++j) {
                float v = acc[mi][ni][j] + bv;
                if (EPI == 0) {
                    ((float*)Cp)[(size_t)(rb + j) * N + cc] = v;
                } else {
                    int e = cc >> 9, pp = cc & 511;
                    ((u16*)Cp)[(((size_t)(rb + j) * 8 + e) << 9) | pp] =
                        f2b(tanhf(v) * gain[pp]);
                }
            }
        }
    }
}

// ---------------------------------------------------------------------------
// Decoder GEMM, 256x128 tile, 512 threads (8 waves, 4x2), double-buffered,
// WITH FUSED COMBINE of the previous chunk: blocks with blockIdx.y ==
// gridDim.y-1 grid-stride the prev chunk's outputs (pe ping-pong makes the
// buffers disjoint; rowsum of prev chunk is final by kernel-boundary order).
// ---------------------------------------------------------------------------
__global__ __launch_bounds__(512)
void k_gemm_dec(const u16* __restrict__ A, const u16* __restrict__ B,
                const float* __restrict__ bias, u16* __restrict__ pe,
                int M, int N, int K, float* __restrict__ rsum,
                const u16* __restrict__ pePrev, const float* __restrict__ prior,
                const float* __restrict__ rsumPrev, float* __restrict__ outp,
                int n0prev, int nPer)
{
    __shared__ __align__(16) u16 As[2][256 * 32];
    __shared__ __align__(16) u16 Bs[2][128 * 32];
    __shared__ float rs[2][256];
    const int tid = threadIdx.x;

    if ((int)blockIdx.y == (int)gridDim.y - 1) {
        // ---- combine role: prev chunk ----
        if (n0prev < 0) return;
        float* wsh = (float*)As;               // reuse LDS
        for (int i = tid; i < nPer * 8; i += 512)
            wsh[i] = prior[(size_t)(n0prev + (i >> 3)) * 8 + (i & 7)]
                   / rsumPrev[i];
        __syncthreads();
        const int total = nPer * 32000;
        const int stride = gridDim.x * 512;
        for (int i = blockIdx.x * 512 + tid; i < total; i += stride) {
            int nl = i / 32000, v = i - nl * 32000;
            float acc = 0.f;
#pragma unroll
            for (int e = 0; e < 8; ++e)
                acc += b2f(pePrev[(size_t)(nl * 8 + e) * 32000 + v])
                     * wsh[nl * 8 + e];
            outp[(size_t)(n0prev + nl) * 32000 + v] = logf(acc + 1e-8f);
        }
        return;
    }

    const int lane = tid & 63, wid = tid >> 6;
    const int wr = wid >> 1, wc = wid & 1;
    const int l15 = lane & 15, l4 = lane >> 4;
    const int row0 = blockIdx.y * 256, col0 = blockIdx.x * 128;

    const int srA = wid * 16 + (lane >> 2);    // 0..127
    const int skA = (lane & 3) * 8;

    auto stage = [&](int buf, int k0) {
        gload16(A + (size_t)(row0 + srA) * K + k0 + skA, &As[buf][wid * 512]);
        gload16(A + (size_t)(row0 + 128 + srA) * K + k0 + skA, &As[buf][4096 + wid * 512]);
        gload16(B + (size_t)(col0 + srA) * K + k0 + skA, &Bs[buf][wid * 512]);
    };

    f32x4 acc[4][4] = {};

    stage(0, 0);
    __syncthreads();
    int cur = 0;
    for (int k0 = 0; k0 < K; k0 += 32) {
        if (k0 + 32 < K) stage(cur ^ 1, k0 + 32);

        short8 af[4], bfv[4];
#pragma unroll
        for (int i = 0; i < 4; ++i)
            af[i]  = *(const short8*)&As[cur][(wr * 64 + i * 16 + l15) * 32 + l4 * 8];
#pragma unroll
        for (int i = 0; i < 4; ++i)
            bfv[i] = *(const short8*)&Bs[cur][(wc * 64 + i * 16 + l15) * 32 + l4 * 8];
#pragma unroll
        for (int mi = 0; mi < 4; ++mi)
#pragma unroll
            for (int ni = 0; ni < 4; ++ni)
                acc[mi][ni] = __builtin_amdgcn_mfma_f32_16x16x32_bf16(
                    af[mi], bfv[ni], acc[mi][ni], 0, 0, 0);
        __syncthreads();
        cur ^= 1;
    }

#pragma unroll
    for (int mi = 0; mi < 4; ++mi) {
#pragma unroll
        for (int j = 0; j < 4; ++j) {
            int rloc = wr * 64 + mi * 16 + l4 * 4 + j;
            float rsub = 0.f;
#pragma unroll
            for (int ni = 0; ni < 4; ++ni) {
                int cc = col0 + wc * 64 + ni * 16 + l15;
                float pv = expf(fminf(acc[mi][ni][j] + bias[cc], 80.f));
                pe[(size_t)(row0 + rloc) * N + cc] = f2b(pv);
                rsub += pv;
            }
#pragma unroll
            for (int o = 1; o < 16; o <<= 1) rsub += __shfl_xor(rsub, o, 64);
            if (l15 == 0) rs[wc][rloc] = rsub;
        }
    }
    __syncthreads();
    if (tid < 256)
        atomicAdd(&rsum[row0 + tid], rs[0][tid] + rs[1][tid]);
}

// ---------------------------------------------------------------------------
// Persistent-weight cooperative LSTM layer, FENCELESS protocol (round-7
// proven, worker path byte-identical). Blocks >= nb are CONVERSION HELPERS
// (layer 0): grid-stride f2b of the CvtJobs list in the RNN's latency shadow.
// ---------------------------------------------------------------------------
template <int DH>
__global__ void __launch_bounds__(512)
k_rnn(const float* __restrict__ xg,    // (1024, 4*DH) f32
      const u16* __restrict__ W,       // (4*DH, DH) bf16
      const float* __restrict__ h0f,   // (16, DH) f32
      const float* __restrict__ c0f,   // (16, DH) f32
      u16* __restrict__ y,             // (1024, DH) bf16
      unsigned* __restrict__ bar,      // nb slots, stride 32 uints, zeroed
      int nb, CvtJobs jobs)
{
    if ((int)blockIdx.x >= nb) {
        const int hb = blockIdx.x - nb, nh = gridDim.x - nb;
        for (int j = 0; j < jobs.njobs; ++j) {
            const float4* s = (const float4*)jobs.s[j];
            short4* d = (short4*)jobs.d[j];
            const int n4 = jobs.n4[j];
            for (int i = hb * 512 + threadIdx.x; i < n4; i += nh * 512) {
                float4 v = s[i];
                short4 o;
                o.x = (short)f2b(v.x); o.y = (short)f2b(v.y);
                o.z = (short)f2b(v.z); o.w = (short)f2b(v.w);
                d[i] = o;
            }
        }
        return;
    }

    constexpr int DH2 = DH / 2;
    constexpr int NSH = DH2 / 32;      // MFMA k-steps per K-half
    constexpr int NL  = 16 * DH / 4 / 512;   // u64 h-loads per thread
    constexpr int RW  = DH / 4;        // u64 per h row
    constexpr int LDH = DH + 8;        // pad -> 2-way banks (free)
    __shared__ __align__(16) u16 hs[16][LDH];
    __shared__ __align__(16) f32x4 red[8][64];
    __shared__ __align__(16) u16 hout[16][16];

    const int tid = threadIdx.x;
    const int lane = tid & 63, wid = tid >> 6;
    const int g = wid & 3, kh = wid >> 2;
    const int l15 = lane & 15, l4 = lane >> 4;
    const int u0 = blockIdx.x * 16;

    // ---- load W fragments into registers (once) ----
    short8 wfr[NSH];
    {
        const u16* wa = W + (size_t)(g * DH + u0 + l15) * DH + kh * DH2 + l4 * 8;
#pragma unroll
        for (int s = 0; s < NSH; ++s) wfr[s] = *(const short8*)(wa + s * 32);
    }

    const int eb = tid >> 4, eu = tid & 15;      // epilogue mapping (tid<256)
    float c_reg = (tid < 256) ? c0f[(size_t)eb * DH + u0 + eu] : 0.f;

    for (int t = 0; t < 64; ++t) {
        // ---- prefetch xg row into regs ----
        float xpre[4];
        if (tid < 256) {
            const float* xr = xg + (size_t)(t * 16 + eb) * 4 * DH + u0 + eu;
#pragma unroll
            for (int gg = 0; gg < 4; ++gg) xpre[gg] = xr[(size_t)gg * DH];
        }

        // ---- wait for producers + stage h_{t-1} into LDS ----
        if (t == 0) {
            for (int i = tid; i < 16 * DH / 4; i += 512) {
                int r = i / (DH / 4), k4 = i % (DH / 4);
                float4 v = *(const float4*)(h0f + (size_t)r * DH + k4 * 4);
                short4 o;
                o.x = (short)f2b(v.x); o.y = (short)f2b(v.y);
                o.z = (short)f2b(v.z); o.w = (short)f2b(v.w);
                *(short4*)&hs[r][k4 * 4] = o;
            }
            __syncthreads();
        } else {
            if (tid < nb) {
                while (__hip_atomic_load(bar + tid * 32, __ATOMIC_RELAXED,
                                         __HIP_MEMORY_SCOPE_AGENT) < (unsigned)t)
                    __builtin_amdgcn_s_sleep(1);
            }
            __syncthreads();
            // coherent h read from LLC (batched -> pipelined loads)
            const u64* hp = (const u64*)(y + (size_t)(t - 1) * 16 * DH);
            u64 tmp[NL];
#pragma unroll
            for (int j = 0; j < NL; ++j)
                tmp[j] = __hip_atomic_load(hp + tid + j * 512, __ATOMIC_RELAXED,
                                           __HIP_MEMORY_SCOPE_AGENT);
#pragma unroll
            for (int j = 0; j < NL; ++j) {
                int idx = tid + j * 512;
                int r = idx / RW, c = (idx % RW) * 4;
                *(u64*)&hs[r][c] = tmp[j];
            }
            __syncthreads();
        }

        // ---- MFMA from register-resident W ----
        f32x4 acc = {};
#pragma unroll
        for (int s = 0; s < NSH; ++s) {
            short8 hf = *(const short8*)&hs[l15][kh * DH2 + s * 32 + l4 * 8];
            acc = __builtin_amdgcn_mfma_f32_16x16x32_bf16(hf, wfr[s], acc, 0, 0, 0);
        }
        red[wid][lane] = acc;
        __syncthreads();

        // ---- gate math (256 threads: one per (batch, unit)) ----
        if (tid < 256) {
            const int li = (eb >> 2) * 16 + eu, j = eb & 3;
            float gt[4];
#pragma unroll
            for (int gg = 0; gg < 4; ++gg)
                gt[gg] = ((const float*)&red[gg][li])[j]
                       + ((const float*)&red[4 + gg][li])[j]
                       + xpre[gg];
            float si = 1.f / (1.f + expf(-gt[0]));
            float sf = 1.f / (1.f + expf(-gt[1]));
            float so = 1.f / (1.f + expf(-gt[3]));
            c_reg = sf * c_reg + si * tanhf(gt[2]);
            hout[eb][eu] = f2b(so * tanhf(c_reg));
        }
        __syncthreads();

        // ---- coherent h write to LLC (wave 0: 64 x u64) ----
        if (tid < 64) {
            int r = tid >> 2, c4 = (tid & 3) * 4;
            u64 v = *(const u64*)&hout[r][c4];
            __hip_atomic_store((u64*)(y + (size_t)(t * 16 + r) * DH + u0 + c4), v,
                               __ATOMIC_RELAXED, __HIP_MEMORY_SCOPE_AGENT);
        }

        if (t < 63) {
            __syncthreads();   // wave 0 drains its vmcnt before barrier
            if (tid == 0)
                __hip_atomic_store(bar + blockIdx.x * 32, (unsigned)(t + 1),
                                   __ATOMIC_RELAXED, __HIP_MEMORY_SCOPE_AGENT);
        }
    }
}

// ---------------------------------------------------------------------------
// Prior: softmax over 8 experts of out2(1024x1024 bf16) @ prior_W^T(8x1024)
// ---------------------------------------------------------------------------
__global__ __launch_bounds__(256)
void k_prior(const u16* __restrict__ out2, const float* __restrict__ pW,
             float* __restrict__ prior)
{
    const int n = blockIdx.x;
    const int tid = threadIdx.x;
    const int e = tid >> 5, lane = tid & 31;
    const u16* x = out2 + (size_t)n * 1024;
    const float* w = pW + (size_t)e * 1024;
    float s = 0.f;
    for (int k = lane; k < 1024; k += 32) s += b2f(x[k]) * w[k];
#pragma unroll
    for (int o = 16; o; o >>= 1) s += __shfl_down(s, o, 32);
    __shared__ float es[8];
    if (lane == 0) es[e] = s;
    __syncthreads();
    if (tid == 0) {
        float m = -1e30f;
        for (int i = 0; i < 8; ++i) m = fmaxf(m, es[i]);
        float Z = 0.f, ex[8];
        for (int i = 0; i < 8; ++i) { ex[i] = expf(es[i] - m); Z += ex[i]; }
        for (int i = 0; i < 8; ++i) prior[(size_t)n * 8 + i] = ex[i] / Z;
    }
}

// ---------------------------------------------------------------------------
// Standalone combine (tail chunk + 128-row fallback).
// ---------------------------------------------------------------------------
__global__ __launch_bounds__(128)
void k_combine(const u16* __restrict__ pe, const float* __restrict__ prior,
               const float* __restrict__ rsum, float* __restrict__ out, int n0)
{
    const int v2 = blockIdx.x * 128 + threadIdx.x;
    const int nl = blockIdx.y;
    __shared__ float w[8];
    if (threadIdx.x < 8)
        w[threadIdx.x] = prior[(size_t)(n0 + nl) * 8 + threadIdx.x]
                       / rsum[nl * 8 + threadIdx.x];
    __syncthreads();
    float a0 = 0.f, a1 = 0.f;
#pragma unroll
    for (int e = 0; e < 8; ++e) {
        unsigned pv = *(const unsigned*)&pe[(size_t)(nl * 8 + e) * 32000 + v2 * 2];
        a0 += b2f((u16)(pv & 0xffff)) * w[e];
        a1 += b2f((u16)(pv >> 16)) * w[e];
    }
    float2 o;
    o.x = logf(a0 + 1e-8f);
    o.y = logf(a1 + 1e-8f);
    *(float2*)&out[(size_t)(n0 + nl) * 32000 + v2 * 2] = o;
}

// ---------------------------------------------------------------------------
extern "C" void kernel_launch(void* const* d_in, const int* in_sizes, int n_in,
                              void* d_out, int out_size, void* d_ws, size_t ws_size,
                              hipStream_t stream)
{
    const int*   tok  = (const int*)d_in[0];
    const float* h0   = (const float*)d_in[1];
    const float* c0   = (const float*)d_in[2];
    const float* h1   = (const float*)d_in[3];
    const float* c1   = (const float*)d_in[4];
    const float* h2   = (const float*)d_in[5];
    const float* c2   = (const float*)d_in[6];
    const float* emb  = (const float*)d_in[7];
    const float* Wih0 = (const float*)d_in[8];
    const float* Whh0 = (const float*)d_in[9];
    const float* b0   = (const float*)d_in[10];
    const float* Wih1 = (const float*)d_in[11];
    const float* Whh1 = (const float*)d_in[12];
    const float* b1   = (const float*)d_in[13];
    const float* Wih2 = (const float*)d_in[14];
    const float* Whh2 = (const float*)d_in[15];
    const float* b2   = (const float*)d_in[16];
    const float* priW = (const float*)d_in[17];
    const float* latW = (const float*)d_in[18];
    const float* latb = (const float*)d_in[19];
    const float* decW = (const float*)d_in[20];
    const float* decb = (const float*)d_in[21];
    const float* gain = (const float*)d_in[22];

    // bump allocator (256B aligned)
    char* p = (char*)d_ws;
    auto alloc = [&](size_t bytes) {
        char* r = p; p += (bytes + 255) & ~(size_t)255; return r;
    };
    // ---- persistent region ----
    u16* Whh0b = (u16*)alloc(6144ull * 1536 * 2);
    u16* Whh1b = (u16*)alloc(6144ull * 1536 * 2);
    u16* Whh2b = (u16*)alloc(4096ull * 1024 * 2);
    u16* latWb = (u16*)alloc(4096ull * 1024 * 2);
    u16* decWb = (u16*)alloc(32000ull * 512 * 2);
    u16* latb16 = (u16*)alloc(8192ull * 512 * 2);
    float* pri   = (float*)alloc(8192 * 4);
    float* rowsum = (float*)alloc(8192 * 4);      // one slot per expert-row
    u16* out2 = (u16*)alloc(1024ull * 1024 * 2);
    unsigned* bars = (unsigned*)alloc(3 * 96 * 32 * 4);  // 3 layers x 96 slots
    // ---- transient region (dead before decoder; pe ping-pong aliases it) ---
    char* trans = p;
    u16* Wih0b = (u16*)alloc(6144ull * 512 * 2);
    u16* Wih1b = (u16*)alloc(6144ull * 1536 * 2);
    u16* Wih2b = (u16*)alloc(4096ull * 1536 * 2);
    u16* x0 = (u16*)alloc(1024ull * 512 * 2);
    u16* x1 = (u16*)alloc(1024ull * 1536 * 2);
    u16* x2 = (u16*)alloc(1024ull * 1536 * 2);
    float* xg = (float*)alloc(1024ull * 6144 * 4);
    size_t cap = ws_size - (size_t)(trans - (char*)d_ws);
    int chunkRows;
    bool fused;
    if      (cap >= 2ull * 1024 * 32000 * 2) { chunkRows = 1024; fused = true; }
    else if (cap >= 2ull * 512 * 32000 * 2)  { chunkRows = 512;  fused = true; }
    else if (cap >= 2ull * 256 * 32000 * 2)  { chunkRows = 256;  fused = true; }
    else                                     { chunkRows = 128;  fused = false; }
    int nPer = chunkRows / 8;
    size_t chunkElems = (size_t)chunkRows * 32000;
    u16* pe0 = (u16*)trans;
    u16* pe1 = pe0 + chunkElems;     // only used when fused

    // zero flag slots + rowsum (once; chunks use disjoint slices)
    hipMemsetAsync(bars, 0, 3 * 96 * 32 * 4, stream);
    hipMemsetAsync(rowsum, 0, 8192 * 4, stream);

    // pre-RNN conversions + embedding (only what layer 0 needs)
    k_f2b<<<9216, 256, 0, stream>>>(Whh0, Whh0b, 2359296);
    k_f2b<<<3072, 256, 0, stream>>>(Wih0, Wih0b, 786432);
    k_embed<<<512, 256, 0, stream>>>(tok, emb, x0);

    // ---- layer 0 (512 -> 1536), carries remaining conversions ----
    k_gemm<0><<<dim3(48, 8), 256, 0, stream>>>(
        x0, Wih0b, b0, xg, 1024, 6144, 512, nullptr, nullptr);
    {
        unsigned* bar = bars;
        int nb = 96;
        CvtJobs jobs;
        jobs.s[0] = Whh1; jobs.d[0] = Whh1b; jobs.n4[0] = 2359296;
        jobs.s[1] = Whh2; jobs.d[1] = Whh2b; jobs.n4[1] = 1048576;
        jobs.s[2] = Wih1; jobs.d[2] = Wih1b; jobs.n4[2] = 2359296;
        jobs.s[3] = Wih2; jobs.d[3] = Wih2b; jobs.n4[3] = 1572864;
        jobs.s[4] = latW; jobs.d[4] = latWb; jobs.n4[4] = 1048576;
        jobs.s[5] = decW; jobs.d[5] = decWb; jobs.n4[5] = 4096000;
        jobs.njobs = 6;
        void* args[] = {(void*)&xg, (void*)&Whh0b, (void*)&h0, (void*)&c0,
                        (void*)&x1, (void*)&bar, (void*)&nb, (void*)&jobs};
        hipLaunchCooperativeKernel(reinterpret_cast<void*>(&k_rnn<1536>),
                                   dim3(256), dim3(512), args, 0, stream);
    }

    // ---- layer 1 (1536 -> 1536) ----
    k_gemm<0><<<dim3(48, 8), 256, 0, stream>>>(
        x1, Wih1b, b1, xg, 1024, 6144, 1536, nullptr, nullptr);
    {
        unsigned* bar = bars + 96 * 32;
        int nb = 96;
        CvtJobs jobs;
        jobs.njobs = 0;
        void* args[] = {(void*)&xg, (void*)&Whh1b, (void*)&h1, (void*)&c1,
                        (void*)&x2, (void*)&bar, (void*)&nb, (void*)&jobs};
        hipLaunchCooperativeKernel(reinterpret_cast<void*>(&k_rnn<1536>),
                                   dim3(96), dim3(512), args, 0, stream);
    }

    // ---- layer 2 (1536 -> 1024) ----
    k_gemm<0><<<dim3(32, 8), 256, 0, stream>>>(
        x2, Wih2b, b2, xg, 1024, 4096, 1536, nullptr, nullptr);
    {
        unsigned* bar = bars + 2 * 96 * 32;
        int nb = 64;
        CvtJobs jobs;
        jobs.njobs = 0;
        void* args[] = {(void*)&xg, (void*)&Whh2b, (void*)&h2, (void*)&c2,
                        (void*)&out2, (void*)&bar, (void*)&nb, (void*)&jobs};
        hipLaunchCooperativeKernel(reinterpret_cast<void*>(&k_rnn<1024>),
                                   dim3(64), dim3(512), args, 0, stream);
    }

    // ---- MoS head ----
    k_prior<<<1024, 256, 0, stream>>>(out2, priW, pri);
    k_gemm<1><<<dim3(32, 8), 256, 0, stream>>>(
        out2, latWb, latb, latb16, 1024, 4096, 1024, gain, nullptr);

    // ---- decoder ----
    if (fused) {
        const int rowTiles = chunkRows / 256;
        const int nChunks = 1024 / nPer;
        for (int ci = 0; ci < nChunks; ++ci) {
            int nb = ci * nPer;
            u16* peCur = (ci & 1) ? pe1 : pe0;
            const u16* pePrev = (ci & 1) ? pe0 : pe1;
            int n0prev = nb - nPer;
            const float* rsPrev = rowsum + (size_t)(n0prev < 0 ? 0 : n0prev) * 8;
            k_gemm_dec<<<dim3(250, rowTiles + 1), 512, 0, stream>>>(
                latb16 + (size_t)nb * 8 * 512, decWb, decb, peCur,
                chunkRows, 32000, 512, rowsum + (size_t)nb * 8,
                pePrev, pri, rsPrev, (float*)d_out, n0prev, nPer);
        }
        // tail combine (last chunk)
        int n0t = 1024 - nPer;
        const u16* peLast = ((nChunks - 1) & 1) ? pe1 : pe0;
        k_combine<<<dim3(125, nPer), 128, 0, stream>>>(
            peLast, pri, rowsum + (size_t)n0t * 8, (float*)d_out, n0t);
    } else {
        for (int nb = 0; nb < 1024; nb += nPer) {
            const u16* Ach = latb16 + (size_t)nb * 8 * 512;
            float* rsumc = rowsum + (size_t)nb * 8;
            k_gemm<2><<<dim3(250, chunkRows / 128), 256, 0, stream>>>(
                Ach, decWb, decb, pe0, chunkRows, 32000, 512, nullptr, rsumc);
            k_combine<<<dim3(125, nPer), 128, 0, stream>>>(
                pe0, pri, rsumc, (float*)d_out, nb);
        }
    }
}